// Round 7
// baseline (236.149 us; speedup 1.0000x reference)
//
#include <hip/hip_runtime.h>

#define C 128
#define NEG_SLOPE 0.2f
#define SM_EPS 1e-16f
#define BKT_SHIFT 8            // 256 nodes per bucket (write-coherent bin runs)
#define BKT_MASK 255
#define BIN_CHUNK 8192
#define WP 136                 // LDS pitch (u16) for h-writeback slice

typedef unsigned int uint32;
typedef __attribute__((ext_vector_type(8))) short bf16x8;
typedef __attribute__((ext_vector_type(4))) float f32x4;

// ---- bf16 helpers (RNE) ----
static __device__ __forceinline__ unsigned short f2bf(float f) {
    uint32 u = __float_as_uint(f);
    uint32 r = 0x7FFFu + ((u >> 16) & 1u);
    return (unsigned short)((u + r) >> 16);
}
static __device__ __forceinline__ uint32 f2bf2(float lo, float hi) {
    return (uint32)f2bf(lo) | ((uint32)f2bf(hi) << 16);
}

// ---- W -> bf16, fragment-ordered: Wf[(t*4+kk)*256 + lane*4 + j2] ----
// frag for (t,kk): lane holds B[n=t*16+(lane&15)][k=kk*32+(lane>>4)*8 .. +7]
__global__ __launch_bounds__(256) void cvtw_kernel(const float* __restrict__ W,
                                                   uint32* __restrict__ Wf) {
    int gid = blockIdx.x * 256 + threadIdx.x;       // 0..8191
    int j2   = gid & 3;
    int lane = (gid >> 2) & 63;
    int tile = gid >> 8;                            // t*4+kk
    int t = tile >> 2, kk = tile & 3;
    int n = t * 16 + (lane & 15);
    int k = kk * 32 + (lane >> 4) * 8 + j2 * 2;
    Wf[gid] = f2bf2(W[k * C + n], W[(k + 1) * C + n]);
}

// ---- MFMA GEMM (no input LDS) + alpha reductions + bf16 h + fused bucket hist ----
__global__ __launch_bounds__(256) void gemm_hist_kernel(
    const float* __restrict__ x, const uint32* __restrict__ Wf,
    const float* __restrict__ a_src, const float* __restrict__ a_dst,
    unsigned short* __restrict__ hb, float* __restrict__ as_out,
    float* __restrict__ ad_out, int N,
    const int* __restrict__ dst, int* __restrict__ bucket_cnt, int E, int total, int NB)
{
    __shared__ __align__(16) unsigned short slice[4][16 * WP];
    __shared__ int bhist[256];

    const int tid  = threadIdx.x;
    const int lane = tid & 63;
    const int w    = tid >> 6;
    const int row0 = blockIdx.x * 64;
    const int m16  = lane & 15;
    const int q    = lane >> 4;

    bhist[tid] = 0;

    const int row = row0 + w * 16 + m16;
    const bool rv = (row < N);
    const float* xr_p = x + (size_t)(rv ? row : 0) * C + q * 8;

    // load this lane's 128B of its x row (covers k = kk*32+q*8 .. +7, kk=0..3)
    float4 xr[8];
    #pragma unroll
    for (int kk = 0; kk < 4; ++kk) {
        xr[kk * 2]     = rv ? *(const float4*)(xr_p + kk * 32)     : make_float4(0, 0, 0, 0);
        xr[kk * 2 + 1] = rv ? *(const float4*)(xr_p + kk * 32 + 4) : make_float4(0, 0, 0, 0);
    }

    f32x4 acc[8];
    const f32x4 zz = {0.f, 0.f, 0.f, 0.f};
    #pragma unroll
    for (int t = 0; t < 8; ++t) acc[t] = zz;

    #pragma unroll
    for (int kk = 0; kk < 4; ++kk) {
        union { bf16x8 v; uint32 u[4]; } au;
        float4 p0 = xr[kk * 2], p1 = xr[kk * 2 + 1];
        au.u[0] = f2bf2(p0.x, p0.y); au.u[1] = f2bf2(p0.z, p0.w);
        au.u[2] = f2bf2(p1.x, p1.y); au.u[3] = f2bf2(p1.z, p1.w);
        #pragma unroll
        for (int t = 0; t < 8; ++t) {
            bf16x8 b = *(const bf16x8*)&Wf[((t * 4 + kk) * 64 + lane) * 4];
            acc[t] = __builtin_amdgcn_mfma_f32_16x16x32_bf16(au.v, b, acc[t], 0, 0, 0);
        }
    }

    // alpha reductions: C/D layout col = t*16+m16, row = q*4+r
    float ps[4] = {0.f, 0.f, 0.f, 0.f}, pd[4] = {0.f, 0.f, 0.f, 0.f};
    #pragma unroll
    for (int t = 0; t < 8; ++t) {
        float av = a_src[t * 16 + m16];
        float dv = a_dst[t * 16 + m16];
        #pragma unroll
        for (int r = 0; r < 4; ++r) {
            ps[r] += acc[t][r] * av;
            pd[r] += acc[t][r] * dv;
        }
    }
    #pragma unroll
    for (int r = 0; r < 4; ++r) {
        #pragma unroll
        for (int off = 1; off < 16; off <<= 1) {
            ps[r] += __shfl_xor(ps[r], off, 64);
            pd[r] += __shfl_xor(pd[r], off, 64);
        }
    }
    if (m16 == 0) {
        #pragma unroll
        for (int r = 0; r < 4; ++r) {
            int rr = row0 + w * 16 + q * 4 + r;
            if (rr < N) { as_out[rr] = ps[r]; ad_out[rr] = pd[r]; }
        }
    }

    // h writeback via LDS transform
    #pragma unroll
    for (int t = 0; t < 8; ++t)
        #pragma unroll
        for (int r = 0; r < 4; ++r)
            slice[w][(q * 4 + r) * WP + t * 16 + m16] = f2bf(acc[t][r]);
    __syncthreads();
    #pragma unroll
    for (int it = 0; it < 4; ++it) {
        int r = it * 4 + q;
        int rr = row0 + w * 16 + r;
        if (rr < N) {
            bf16x8 v = *(const bf16x8*)&slice[w][r * WP + m16 * 8];
            *(bf16x8*)&hb[(size_t)rr * C + m16 * 8] = v;
        }
    }

    // fused bucket histogram (grid-stride over edges + self loops)
    for (int i = blockIdx.x * 256 + tid; i < total; i += gridDim.x * 256) {
        int d = (i < E) ? dst[i] : (i - E);
        atomicAdd(&bhist[d >> BKT_SHIFT], 1);
    }
    __syncthreads();
    if (tid < NB && bhist[tid]) atomicAdd(&bucket_cnt[tid], bhist[tid]);
}

// ---- scan of bucket counts (NB <= 256, single block) ----
__global__ __launch_bounds__(256) void scan_off_kernel(
    const int* __restrict__ bucket_cnt, int* __restrict__ bucket_off,
    int* __restrict__ bucket_cursor, int* __restrict__ row_start,
    int NB, int N, int total)
{
    __shared__ int wave_tot[4];
    const int tid = threadIdx.x, lane = tid & 63, wid = tid >> 6;
    int v = (tid < NB) ? bucket_cnt[tid] : 0;
    int x = v;
    #pragma unroll
    for (int off = 1; off < 64; off <<= 1) {
        int t = __shfl_up(x, off, 64);
        if (lane >= off) x += t;
    }
    if (lane == 63) wave_tot[wid] = x;
    __syncthreads();
    int wbase = 0;
    #pragma unroll
    for (int w = 0; w < 4; ++w) wbase += (w < wid) ? wave_tot[w] : 0;
    int excl = wbase + x - v;
    if (tid < NB) { bucket_off[tid] = excl; bucket_cursor[tid] = excl; }
    if (tid == 0) { bucket_off[NB] = total; row_start[N] = total; }
}

// ---- bin: scatter into bucket-contiguous packed runs (~168B/run) ----
__global__ __launch_bounds__(256) void bin_kernel(
    const int* __restrict__ src, const int* __restrict__ dst,
    int* __restrict__ bucket_cursor, uint32* __restrict__ packed,
    int E, int total, int NB)
{
    __shared__ int hist[256];
    __shared__ int base[256];
    const int tid = threadIdx.x;
    const int start = blockIdx.x * BIN_CHUNK;
    const int end = min(start + BIN_CHUNK, total);

    hist[tid] = 0;
    __syncthreads();
    for (int i = start + tid; i < end; i += 256) {
        int d = (i < E) ? dst[i] : (i - E);
        atomicAdd(&hist[d >> BKT_SHIFT], 1);
    }
    __syncthreads();
    if (tid < NB) {
        int c = hist[tid];
        base[tid] = c ? atomicAdd(&bucket_cursor[tid], c) : 0;
    }
    hist[tid] = 0;
    __syncthreads();
    for (int i = start + tid; i < end; i += 256) {
        int s = (i < E) ? src[i] : (i - E);
        int d = (i < E) ? dst[i] : (i - E);
        int b = d >> BKT_SHIFT;
        int pos = base[b] + atomicAdd(&hist[b], 1);
        packed[pos] = ((uint32)s << BKT_SHIFT) | (uint32)(d & BKT_MASK);
    }
}

// ---- build: per-bucket fine counting sort + fused e; 1024 threads/block ----
// csr entry = uint2{ src, float_bits(leaky(as[src] + ad[dst])) }
__global__ __launch_bounds__(1024) void build_kernel(
    const uint32* __restrict__ packed, const int* __restrict__ bucket_off,
    const float* __restrict__ as, const float* __restrict__ ad,
    int* __restrict__ row_start, uint2* __restrict__ csr, int N)
{
    __shared__ int cnt[256];
    __shared__ int cur[256];
    __shared__ float adl[256];
    __shared__ int wave_tot[4];
    const int tid = threadIdx.x;
    const int b = blockIdx.x;
    const int off = bucket_off[b];
    const int end = bucket_off[b + 1];

    if (tid < 256) {
        cnt[tid] = 0;
        int g = (b << BKT_SHIFT) + tid;
        adl[tid] = (g < N) ? ad[g] : 0.f;
    }
    __syncthreads();
    for (int j = off + tid; j < end; j += 1024)
        atomicAdd(&cnt[packed[j] & BKT_MASK], 1);
    __syncthreads();

    int v = 0, x = 0;
    if (tid < 256) {
        const int lane = tid & 63, wid = tid >> 6;
        v = cnt[tid]; x = v;
        #pragma unroll
        for (int o = 1; o < 64; o <<= 1) {
            int t = __shfl_up(x, o, 64);
            if (lane >= o) x += t;
        }
        if (lane == 63) wave_tot[wid] = x;
    }
    __syncthreads();
    if (tid < 256) {
        const int wid = tid >> 6;
        int wbase = 0;
        #pragma unroll
        for (int w = 0; w < 4; ++w) wbase += (w < wid) ? wave_tot[w] : 0;
        int excl = wbase + x - v;
        int g = (b << BKT_SHIFT) + tid;
        if (g < N) row_start[g] = off + excl;
        cur[tid] = excl;
    }
    __syncthreads();

    for (int j = off + tid; j < end; j += 1024) {
        uint32 p = packed[j];
        int l = (int)(p & BKT_MASK);
        int s = (int)(p >> BKT_SHIFT);
        float e = as[s] + adl[l];
        e = (e > 0.f) ? e : NEG_SLOPE * e;
        int pos = atomicAdd(&cur[l], 1);
        csr[off + pos] = make_uint2((uint32)s, __float_as_uint(e));
    }
}

// ---- fused softmax + gather-aggregate + bias + relu (register-resident) ----
__global__ __launch_bounds__(256) void gather_kernel(
    const uint2* __restrict__ csr, const int* __restrict__ row_start,
    const unsigned short* __restrict__ hb, const float* __restrict__ bias,
    float* __restrict__ out, int N)
{
    const int w    = threadIdx.x >> 6;
    const int lane = threadIdx.x & 63;
    const int d = blockIdx.x * 4 + w;
    if (d >= N) return;                     // no barriers below: safe

    const int beg = row_start[d];
    const int deg = row_start[d + 1] - beg;
    const int c2 = lane << 1;
    float a0 = 0.f, a1 = 0.f;

    if (deg <= 64) {
        uint2 ent = (lane < deg) ? csr[beg + lane] : make_uint2(0u, 0xFF800000u);
        float e = __uint_as_float(ent.y);
        float m = e;
        #pragma unroll
        for (int off = 32; off > 0; off >>= 1) m = fmaxf(m, __shfl_xor(m, off, 64));
        float p = (lane < deg) ? __expf(e - m) : 0.f;
        float ssum = p;
        #pragma unroll
        for (int off = 32; off > 0; off >>= 1) ssum += __shfl_xor(ssum, off, 64);
        float wgt = p * (1.f / (ssum + SM_EPS));

        int t = 0;
        for (; t + 4 <= deg; t += 4) {
            int s0 = __shfl((int)ent.x, t, 64),     s1 = __shfl((int)ent.x, t + 1, 64);
            int s2 = __shfl((int)ent.x, t + 2, 64), s3 = __shfl((int)ent.x, t + 3, 64);
            float w0 = __shfl(wgt, t, 64),     w1 = __shfl(wgt, t + 1, 64);
            float w2 = __shfl(wgt, t + 2, 64), w3 = __shfl(wgt, t + 3, 64);
            uint32 u0 = *(const uint32*)&hb[(size_t)s0 * C + c2];
            uint32 u1 = *(const uint32*)&hb[(size_t)s1 * C + c2];
            uint32 u2 = *(const uint32*)&hb[(size_t)s2 * C + c2];
            uint32 u3 = *(const uint32*)&hb[(size_t)s3 * C + c2];
            a0 += __uint_as_float(u0 << 16) * w0 + __uint_as_float(u1 << 16) * w1
                + __uint_as_float(u2 << 16) * w2 + __uint_as_float(u3 << 16) * w3;
            a1 += __uint_as_float(u0 & 0xffff0000u) * w0 + __uint_as_float(u1 & 0xffff0000u) * w1
                + __uint_as_float(u2 & 0xffff0000u) * w2 + __uint_as_float(u3 & 0xffff0000u) * w3;
        }
        for (; t < deg; ++t) {
            int s0 = __shfl((int)ent.x, t, 64);
            float w0 = __shfl(wgt, t, 64);
            uint32 u0 = *(const uint32*)&hb[(size_t)s0 * C + c2];
            a0 += __uint_as_float(u0 << 16) * w0;
            a1 += __uint_as_float(u0 & 0xffff0000u) * w0;
        }
    } else if (deg <= 128) {
        uint2 ea = (lane < deg) ? csr[beg + lane] : make_uint2(0u, 0xFF800000u);
        uint2 eb = (64 + lane < deg) ? csr[beg + 64 + lane] : make_uint2(0u, 0xFF800000u);
        float e0 = __uint_as_float(ea.y), e1 = __uint_as_float(eb.y);
        float m = fmaxf(e0, e1);
        #pragma unroll
        for (int off = 32; off > 0; off >>= 1) m = fmaxf(m, __shfl_xor(m, off, 64));
        float p0 = (lane < deg) ? __expf(e0 - m) : 0.f;
        float p1 = (64 + lane < deg) ? __expf(e1 - m) : 0.f;
        float ssum = p0 + p1;
        #pragma unroll
        for (int off = 32; off > 0; off >>= 1) ssum += __shfl_xor(ssum, off, 64);
        float inv = 1.f / (ssum + SM_EPS);
        float wa = p0 * inv, wb = p1 * inv;
        for (int t = 0; t < deg; ++t) {
            int s0; float w0;
            if (t < 64) { s0 = __shfl((int)ea.x, t, 64); w0 = __shfl(wa, t, 64); }
            else        { s0 = __shfl((int)eb.x, t - 64, 64); w0 = __shfl(wb, t - 64, 64); }
            uint32 u0 = *(const uint32*)&hb[(size_t)s0 * C + c2];
            a0 += __uint_as_float(u0 << 16) * w0;
            a1 += __uint_as_float(u0 & 0xffff0000u) * w0;
        }
    } else {
        float m = -INFINITY;
        for (int t = lane; t < deg; t += 64)
            m = fmaxf(m, __uint_as_float(csr[beg + t].y));
        #pragma unroll
        for (int off = 32; off > 0; off >>= 1) m = fmaxf(m, __shfl_xor(m, off, 64));
        float ssum = 0.f;
        for (int t = lane; t < deg; t += 64)
            ssum += __expf(__uint_as_float(csr[beg + t].y) - m);
        #pragma unroll
        for (int off = 32; off > 0; off >>= 1) ssum += __shfl_xor(ssum, off, 64);
        float inv = 1.f / (ssum + SM_EPS);
        for (int t0 = 0; t0 < deg; t0 += 64) {
            int nc = min(64, deg - t0);
            uint2 ent = (lane < nc) ? csr[beg + t0 + lane] : make_uint2(0u, 0xFF800000u);
            float wl = (lane < nc) ? __expf(__uint_as_float(ent.y) - m) * inv : 0.f;
            for (int t = 0; t < nc; ++t) {
                int s0 = __shfl((int)ent.x, t, 64);
                float w0 = __shfl(wl, t, 64);
                uint32 u0 = *(const uint32*)&hb[(size_t)s0 * C + c2];
                a0 += __uint_as_float(u0 << 16) * w0;
                a1 += __uint_as_float(u0 & 0xffff0000u) * w0;
            }
        }
    }

    float2 b2 = *(const float2*)&bias[c2];
    a0 = fmaxf(a0 + b2.x, 0.f);
    a1 = fmaxf(a1 + b2.y, 0.f);
    *(float2*)&out[(size_t)d * C + c2] = make_float2(a0, a1);
}

extern "C" void kernel_launch(void* const* d_in, const int* in_sizes, int n_in,
                              void* d_out, int out_size, void* d_ws, size_t ws_size,
                              hipStream_t stream) {
    const float* x     = (const float*)d_in[0];
    const float* W     = (const float*)d_in[1];
    const float* a_src = (const float*)d_in[2];
    const float* a_dst = (const float*)d_in[3];
    const float* bias  = (const float*)d_in[4];
    const int*   edge  = (const int*)d_in[5];

    const int N = in_sizes[0] / C;
    const int E = in_sizes[5] / 2;
    const int total = E + N;
    const int* src = edge;
    const int* dst = edge + E;
    float* out = (float*)d_out;

    const int NB = (N + BKT_MASK) >> BKT_SHIFT;   // 196 buckets

    // workspace (4B units):
    // hb[N*C/2] | as[N] | ad[N] | row_start[N+2 pad->8B align] | packed[total]
    // | csr[2*total] | Wf[8192] | bucket_cnt[NB] | bucket_off[NB+1] | bucket_cursor[NB]
    float* ws = (float*)d_ws;
    unsigned short* hb = (unsigned short*)ws;
    float* as = (float*)(hb + (size_t)N * C);
    float* ad = as + N;
    int* row_start     = (int*)(ad + N);
    uint32* packed     = (uint32*)(row_start + (N + 2));   // +2 keeps csr 8B-aligned
    uint2* csr         = (uint2*)(packed + total);
    uint32* Wf         = (uint32*)(csr + total);
    int* bucket_cnt    = (int*)(Wf + 8192);
    int* bucket_off    = bucket_cnt + NB;
    int* bucket_cursor = bucket_off + (NB + 1);

    hipMemsetAsync(bucket_cnt, 0, NB * sizeof(int), stream);
    cvtw_kernel<<<32, 256, 0, stream>>>(W, Wf);
    gemm_hist_kernel<<<(N + 63) / 64, 256, 0, stream>>>(
        x, Wf, a_src, a_dst, hb, as, ad, N, dst, bucket_cnt, E, total, NB);
    scan_off_kernel<<<1, 256, 0, stream>>>(bucket_cnt, bucket_off, bucket_cursor,
                                           row_start, NB, N, total);
    bin_kernel<<<(total + BIN_CHUNK - 1) / BIN_CHUNK, 256, 0, stream>>>(
        src, dst, bucket_cursor, packed, E, total, NB);
    build_kernel<<<NB, 1024, 0, stream>>>(packed, bucket_off, as, ad, row_start, csr, N);
    gather_kernel<<<(N + 3) / 4, 256, 0, stream>>>(csr, row_start, hb, bias, out, N);
}

// Round 8
// 206.814 us; speedup vs baseline: 1.1418x; 1.1418x over previous
//
#include <hip/hip_runtime.h>
#include <hip/hip_fp16.h>

#define C 128
#define NEG_SLOPE 0.2f
#define SM_EPS 1e-16f
#define BKT_SHIFT 8            // 256 nodes per bucket
#define BKT_MASK 255
#define BIN_CHUNK 8192
#define WP 136                 // LDS pitch (u16) for h-writeback slice

typedef unsigned int uint32;
typedef __attribute__((ext_vector_type(8))) short bf16x8;
typedef __attribute__((ext_vector_type(4))) float f32x4;

// ---- bf16 helpers (RNE) ----
static __device__ __forceinline__ unsigned short f2bf(float f) {
    uint32 u = __float_as_uint(f);
    uint32 r = 0x7FFFu + ((u >> 16) & 1u);
    return (unsigned short)((u + r) >> 16);
}
static __device__ __forceinline__ uint32 f2bf2(float lo, float hi) {
    return (uint32)f2bf(lo) | ((uint32)f2bf(hi) << 16);
}
// ---- f16 bit helpers ----
static __device__ __forceinline__ uint32 f2h(float f) {
    __half h = __float2half(f);
    return (uint32)*reinterpret_cast<unsigned short*>(&h);
}
static __device__ __forceinline__ float h2f(uint32 b) {
    unsigned short s = (unsigned short)(b & 0xffffu);
    __half h = *reinterpret_cast<__half*>(&s);
    return __half2float(h);
}

// ---- W -> bf16 fragment-ordered + zero bucket_cnt ----
__global__ __launch_bounds__(256) void cvtw_kernel(const float* __restrict__ W,
                                                   uint32* __restrict__ Wf,
                                                   int* __restrict__ bucket_cnt, int NB) {
    int gid = blockIdx.x * 256 + threadIdx.x;       // 0..8191
    if (blockIdx.x == 0 && threadIdx.x < NB) bucket_cnt[threadIdx.x] = 0;
    int j2   = gid & 3;
    int lane = (gid >> 2) & 63;
    int tile = gid >> 8;                            // t*4+kk
    int t = tile >> 2, kk = tile & 3;
    int n = t * 16 + (lane & 15);
    int k = kk * 32 + (lane >> 4) * 8 + j2 * 2;
    Wf[gid] = f2bf2(W[k * C + n], W[(k + 1) * C + n]);
}

// ---- MFMA GEMM + alpha reductions + bf16 h + fused bucket hist ----
__global__ __launch_bounds__(256) void gemm_hist_kernel(
    const float* __restrict__ x, const uint32* __restrict__ Wf,
    const float* __restrict__ a_src, const float* __restrict__ a_dst,
    unsigned short* __restrict__ hb, float* __restrict__ as_out,
    float* __restrict__ ad_out, int N,
    const int* __restrict__ dst, int* __restrict__ bucket_cnt, int E, int total, int NB)
{
    __shared__ __align__(16) unsigned short slice[4][16 * WP];
    __shared__ int bhist[256];

    const int tid  = threadIdx.x;
    const int lane = tid & 63;
    const int w    = tid >> 6;
    const int row0 = blockIdx.x * 64;
    const int m16  = lane & 15;
    const int q    = lane >> 4;

    bhist[tid] = 0;

    const int row = row0 + w * 16 + m16;
    const bool rv = (row < N);
    const float* xr_p = x + (size_t)(rv ? row : 0) * C + q * 8;

    float4 xr[8];
    #pragma unroll
    for (int kk = 0; kk < 4; ++kk) {
        xr[kk * 2]     = rv ? *(const float4*)(xr_p + kk * 32)     : make_float4(0, 0, 0, 0);
        xr[kk * 2 + 1] = rv ? *(const float4*)(xr_p + kk * 32 + 4) : make_float4(0, 0, 0, 0);
    }

    f32x4 acc[8];
    const f32x4 zz = {0.f, 0.f, 0.f, 0.f};
    #pragma unroll
    for (int t = 0; t < 8; ++t) acc[t] = zz;

    #pragma unroll
    for (int kk = 0; kk < 4; ++kk) {
        union { bf16x8 v; uint32 u[4]; } au;
        float4 p0 = xr[kk * 2], p1 = xr[kk * 2 + 1];
        au.u[0] = f2bf2(p0.x, p0.y); au.u[1] = f2bf2(p0.z, p0.w);
        au.u[2] = f2bf2(p1.x, p1.y); au.u[3] = f2bf2(p1.z, p1.w);
        #pragma unroll
        for (int t = 0; t < 8; ++t) {
            bf16x8 b = *(const bf16x8*)&Wf[((t * 4 + kk) * 64 + lane) * 4];
            acc[t] = __builtin_amdgcn_mfma_f32_16x16x32_bf16(au.v, b, acc[t], 0, 0, 0);
        }
    }

    float ps[4] = {0.f, 0.f, 0.f, 0.f}, pd[4] = {0.f, 0.f, 0.f, 0.f};
    #pragma unroll
    for (int t = 0; t < 8; ++t) {
        float av = a_src[t * 16 + m16];
        float dv = a_dst[t * 16 + m16];
        #pragma unroll
        for (int r = 0; r < 4; ++r) {
            ps[r] += acc[t][r] * av;
            pd[r] += acc[t][r] * dv;
        }
    }
    #pragma unroll
    for (int r = 0; r < 4; ++r) {
        #pragma unroll
        for (int off = 1; off < 16; off <<= 1) {
            ps[r] += __shfl_xor(ps[r], off, 64);
            pd[r] += __shfl_xor(pd[r], off, 64);
        }
    }
    if (m16 == 0) {
        #pragma unroll
        for (int r = 0; r < 4; ++r) {
            int rr = row0 + w * 16 + q * 4 + r;
            if (rr < N) { as_out[rr] = ps[r]; ad_out[rr] = pd[r]; }
        }
    }

    #pragma unroll
    for (int t = 0; t < 8; ++t)
        #pragma unroll
        for (int r = 0; r < 4; ++r)
            slice[w][(q * 4 + r) * WP + t * 16 + m16] = f2bf(acc[t][r]);
    __syncthreads();
    #pragma unroll
    for (int it = 0; it < 4; ++it) {
        int r = it * 4 + q;
        int rr = row0 + w * 16 + r;
        if (rr < N) {
            bf16x8 v = *(const bf16x8*)&slice[w][r * WP + m16 * 8];
            *(bf16x8*)&hb[(size_t)rr * C + m16 * 8] = v;
        }
    }

    for (int i = blockIdx.x * 256 + tid; i < total; i += gridDim.x * 256) {
        int d = (i < E) ? dst[i] : (i - E);
        atomicAdd(&bhist[d >> BKT_SHIFT], 1);
    }
    __syncthreads();
    if (tid < NB && bhist[tid]) atomicAdd(&bucket_cnt[tid], bhist[tid]);
}

// ---- scan of bucket counts (NB <= 256, single block) ----
__global__ __launch_bounds__(256) void scan_off_kernel(
    const int* __restrict__ bucket_cnt, int* __restrict__ bucket_off,
    int* __restrict__ bucket_cursor, int* __restrict__ row_start,
    int NB, int N, int total)
{
    __shared__ int wave_tot[4];
    const int tid = threadIdx.x, lane = tid & 63, wid = tid >> 6;
    int v = (tid < NB) ? bucket_cnt[tid] : 0;
    int x = v;
    #pragma unroll
    for (int off = 1; off < 64; off <<= 1) {
        int t = __shfl_up(x, off, 64);
        if (lane >= off) x += t;
    }
    if (lane == 63) wave_tot[wid] = x;
    __syncthreads();
    int wbase = 0;
    #pragma unroll
    for (int w = 0; w < 4; ++w) wbase += (w < wid) ? wave_tot[w] : 0;
    int excl = wbase + x - v;
    if (tid < NB) { bucket_off[tid] = excl; bucket_cursor[tid] = excl; }
    if (tid == 0) { bucket_off[NB] = total; row_start[N] = total; }
}

// ---- bin: LDS-staged single-read scatter into bucket-contiguous runs ----
__global__ __launch_bounds__(1024) void bin_kernel(
    const int* __restrict__ src, const int* __restrict__ dst,
    int* __restrict__ bucket_cursor, uint32* __restrict__ packed,
    int E, int total, int NB)
{
    __shared__ uint32 lsrc[BIN_CHUNK];           // 32 KB
    __shared__ unsigned short ldst[BIN_CHUNK];   // 16 KB (dst < 65536)
    __shared__ int hist[256];
    __shared__ int base[256];
    const int tid = threadIdx.x;
    const int start = blockIdx.x * BIN_CHUNK;
    const int end = min(start + BIN_CHUNK, total);
    const int n = end - start;

    if (tid < 256) hist[tid] = 0;
    for (int i = start + tid; i < end; i += 1024) {
        int s = (i < E) ? src[i] : (i - E);
        int d = (i < E) ? dst[i] : (i - E);
        lsrc[i - start] = (uint32)s;
        ldst[i - start] = (unsigned short)d;
    }
    __syncthreads();
    for (int j = tid; j < n; j += 1024)
        atomicAdd(&hist[ldst[j] >> BKT_SHIFT], 1);
    __syncthreads();
    if (tid < NB) {
        int c = hist[tid];
        base[tid] = c ? atomicAdd(&bucket_cursor[tid], c) : 0;
    }
    if (tid < 256) hist[tid] = 0;
    __syncthreads();
    for (int j = tid; j < n; j += 1024) {
        int d = ldst[j];
        int b = d >> BKT_SHIFT;
        int pos = base[b] + atomicAdd(&hist[b], 1);
        packed[pos] = (lsrc[j] << BKT_SHIFT) | (uint32)(d & BKT_MASK);
    }
}

// ---- build: per-bucket fine counting sort + fused e; csr = src<<16 | f16(e) ----
__global__ __launch_bounds__(1024) void build_kernel(
    const uint32* __restrict__ packed, const int* __restrict__ bucket_off,
    const float* __restrict__ as, const float* __restrict__ ad,
    int* __restrict__ row_start, uint32* __restrict__ csr, int N)
{
    __shared__ int cnt[256];
    __shared__ int cur[256];
    __shared__ float adl[256];
    __shared__ int wave_tot[4];
    const int tid = threadIdx.x;
    const int b = blockIdx.x;
    const int off = bucket_off[b];
    const int end = bucket_off[b + 1];

    if (tid < 256) {
        cnt[tid] = 0;
        int g = (b << BKT_SHIFT) + tid;
        adl[tid] = (g < N) ? ad[g] : 0.f;
    }
    __syncthreads();
    for (int j = off + tid; j < end; j += 1024)
        atomicAdd(&cnt[packed[j] & BKT_MASK], 1);
    __syncthreads();

    int v = 0, x = 0;
    if (tid < 256) {
        const int lane = tid & 63;
        v = cnt[tid]; x = v;
        #pragma unroll
        for (int o = 1; o < 64; o <<= 1) {
            int t = __shfl_up(x, o, 64);
            if (lane >= o) x += t;
        }
        if (lane == 63) wave_tot[tid >> 6] = x;
    }
    __syncthreads();
    if (tid < 256) {
        const int wid = tid >> 6;
        int wbase = 0;
        #pragma unroll
        for (int w = 0; w < 4; ++w) wbase += (w < wid) ? wave_tot[w] : 0;
        int excl = wbase + x - v;
        int g = (b << BKT_SHIFT) + tid;
        if (g < N) row_start[g] = off + excl;
        cur[tid] = excl;
    }
    __syncthreads();

    for (int j = off + tid; j < end; j += 1024) {
        uint32 p = packed[j];
        int l = (int)(p & BKT_MASK);
        int s = (int)(p >> BKT_SHIFT);
        float e = as[s] + adl[l];
        e = (e > 0.f) ? e : NEG_SLOPE * e;
        int pos = atomicAdd(&cur[l], 1);
        csr[off + pos] = ((uint32)s << 16) | f2h(e);
    }
}

// ---- fused softmax + gather-aggregate + bias + relu (register-resident) ----
// csr entry: src<<16 | f16(e). Broadcast entry: src<<16 | f16(weight).
__global__ __launch_bounds__(256) void gather_kernel(
    const uint32* __restrict__ csr, const int* __restrict__ row_start,
    const unsigned short* __restrict__ hb, const float* __restrict__ bias,
    float* __restrict__ out, int N)
{
    const int w    = threadIdx.x >> 6;
    const int lane = threadIdx.x & 63;
    const int d = blockIdx.x * 4 + w;
    if (d >= N) return;                     // no barriers below: safe

    const int beg = row_start[d];
    const int deg = row_start[d + 1] - beg;
    const int c2 = lane << 1;
    float a0 = 0.f, a1 = 0.f;

    if (deg <= 64) {
        uint32 ent = (lane < deg) ? csr[beg + lane] : 0xFC00u;   // f16 -inf
        float e = h2f(ent);
        float m = e;
        #pragma unroll
        for (int off = 32; off > 0; off >>= 1) m = fmaxf(m, __shfl_xor(m, off, 64));
        float p = (lane < deg) ? __expf(e - m) : 0.f;
        float ssum = p;
        #pragma unroll
        for (int off = 32; off > 0; off >>= 1) ssum += __shfl_xor(ssum, off, 64);
        float wgt = p * (1.f / (ssum + SM_EPS));
        uint32 bc = (ent & 0xffff0000u) | f2h(wgt);

        int t = 0;
        for (; t + 8 <= deg; t += 8) {
            uint32 b0 = (uint32)__shfl((int)bc, t, 64),     b1 = (uint32)__shfl((int)bc, t + 1, 64);
            uint32 b2 = (uint32)__shfl((int)bc, t + 2, 64), b3 = (uint32)__shfl((int)bc, t + 3, 64);
            uint32 b4 = (uint32)__shfl((int)bc, t + 4, 64), b5 = (uint32)__shfl((int)bc, t + 5, 64);
            uint32 b6 = (uint32)__shfl((int)bc, t + 6, 64), b7 = (uint32)__shfl((int)bc, t + 7, 64);
            uint32 u0 = *(const uint32*)&hb[(size_t)(b0 >> 16) * C + c2];
            uint32 u1 = *(const uint32*)&hb[(size_t)(b1 >> 16) * C + c2];
            uint32 u2 = *(const uint32*)&hb[(size_t)(b2 >> 16) * C + c2];
            uint32 u3 = *(const uint32*)&hb[(size_t)(b3 >> 16) * C + c2];
            uint32 u4 = *(const uint32*)&hb[(size_t)(b4 >> 16) * C + c2];
            uint32 u5 = *(const uint32*)&hb[(size_t)(b5 >> 16) * C + c2];
            uint32 u6 = *(const uint32*)&hb[(size_t)(b6 >> 16) * C + c2];
            uint32 u7 = *(const uint32*)&hb[(size_t)(b7 >> 16) * C + c2];
            float w0 = h2f(b0), w1 = h2f(b1), w2 = h2f(b2), w3 = h2f(b3);
            float w4 = h2f(b4), w5 = h2f(b5), w6 = h2f(b6), w7 = h2f(b7);
            a0 += __uint_as_float(u0 << 16) * w0 + __uint_as_float(u1 << 16) * w1
                + __uint_as_float(u2 << 16) * w2 + __uint_as_float(u3 << 16) * w3
                + __uint_as_float(u4 << 16) * w4 + __uint_as_float(u5 << 16) * w5
                + __uint_as_float(u6 << 16) * w6 + __uint_as_float(u7 << 16) * w7;
            a1 += __uint_as_float(u0 & 0xffff0000u) * w0 + __uint_as_float(u1 & 0xffff0000u) * w1
                + __uint_as_float(u2 & 0xffff0000u) * w2 + __uint_as_float(u3 & 0xffff0000u) * w3
                + __uint_as_float(u4 & 0xffff0000u) * w4 + __uint_as_float(u5 & 0xffff0000u) * w5
                + __uint_as_float(u6 & 0xffff0000u) * w6 + __uint_as_float(u7 & 0xffff0000u) * w7;
        }
        for (; t < deg; ++t) {
            uint32 b0 = (uint32)__shfl((int)bc, t, 64);
            uint32 u0 = *(const uint32*)&hb[(size_t)(b0 >> 16) * C + c2];
            float w0 = h2f(b0);
            a0 += __uint_as_float(u0 << 16) * w0;
            a1 += __uint_as_float(u0 & 0xffff0000u) * w0;
        }
    } else if (deg <= 128) {
        uint32 ea = (lane < deg) ? csr[beg + lane] : 0xFC00u;
        uint32 eb = (64 + lane < deg) ? csr[beg + 64 + lane] : 0xFC00u;
        float e0 = h2f(ea), e1 = h2f(eb);
        float m = fmaxf(e0, e1);
        #pragma unroll
        for (int off = 32; off > 0; off >>= 1) m = fmaxf(m, __shfl_xor(m, off, 64));
        float p0 = (lane < deg) ? __expf(e0 - m) : 0.f;
        float p1 = (64 + lane < deg) ? __expf(e1 - m) : 0.f;
        float ssum = p0 + p1;
        #pragma unroll
        for (int off = 32; off > 0; off >>= 1) ssum += __shfl_xor(ssum, off, 64);
        float inv = 1.f / (ssum + SM_EPS);
        uint32 ba = (ea & 0xffff0000u) | f2h(p0 * inv);
        uint32 bb = (eb & 0xffff0000u) | f2h(p1 * inv);
        for (int t = 0; t < deg; ++t) {
            uint32 b0 = (t < 64) ? (uint32)__shfl((int)ba, t, 64)
                                 : (uint32)__shfl((int)bb, t - 64, 64);
            uint32 u0 = *(const uint32*)&hb[(size_t)(b0 >> 16) * C + c2];
            float w0 = h2f(b0);
            a0 += __uint_as_float(u0 << 16) * w0;
            a1 += __uint_as_float(u0 & 0xffff0000u) * w0;
        }
    } else {
        float m = -INFINITY;
        for (int t = lane; t < deg; t += 64)
            m = fmaxf(m, h2f(csr[beg + t]));
        #pragma unroll
        for (int off = 32; off > 0; off >>= 1) m = fmaxf(m, __shfl_xor(m, off, 64));
        float ssum = 0.f;
        for (int t = lane; t < deg; t += 64)
            ssum += __expf(h2f(csr[beg + t]) - m);
        #pragma unroll
        for (int off = 32; off > 0; off >>= 1) ssum += __shfl_xor(ssum, off, 64);
        float inv = 1.f / (ssum + SM_EPS);
        for (int t0 = 0; t0 < deg; t0 += 64) {
            int nc = min(64, deg - t0);
            uint32 ent = (lane < nc) ? csr[beg + t0 + lane] : 0xFC00u;
            float wl = (lane < nc) ? __expf(h2f(ent) - m) * inv : 0.f;
            uint32 bc = (ent & 0xffff0000u) | f2h(wl);
            for (int t = 0; t < nc; ++t) {
                uint32 b0 = (uint32)__shfl((int)bc, t, 64);
                uint32 u0 = *(const uint32*)&hb[(size_t)(b0 >> 16) * C + c2];
                float w0 = h2f(b0);
                a0 += __uint_as_float(u0 << 16) * w0;
                a1 += __uint_as_float(u0 & 0xffff0000u) * w0;
            }
        }
    }

    float2 b2 = *(const float2*)&bias[c2];
    a0 = fmaxf(a0 + b2.x, 0.f);
    a1 = fmaxf(a1 + b2.y, 0.f);
    *(float2*)&out[(size_t)d * C + c2] = make_float2(a0, a1);
}

extern "C" void kernel_launch(void* const* d_in, const int* in_sizes, int n_in,
                              void* d_out, int out_size, void* d_ws, size_t ws_size,
                              hipStream_t stream) {
    const float* x     = (const float*)d_in[0];
    const float* W     = (const float*)d_in[1];
    const float* a_src = (const float*)d_in[2];
    const float* a_dst = (const float*)d_in[3];
    const float* bias  = (const float*)d_in[4];
    const int*   edge  = (const int*)d_in[5];

    const int N = in_sizes[0] / C;
    const int E = in_sizes[5] / 2;
    const int total = E + N;
    const int* src = edge;
    const int* dst = edge + E;
    float* out = (float*)d_out;

    const int NB = (N + BKT_MASK) >> BKT_SHIFT;   // 196 buckets

    // workspace (4B units):
    // hb[N*C/2] | as[N] | ad[N] | row_start[N+2] | packed[total] | csr[total]
    // | Wf[8192] | bucket_cnt[NB] | bucket_off[NB+1] | bucket_cursor[NB]
    float* ws = (float*)d_ws;
    unsigned short* hb = (unsigned short*)ws;
    float* as = (float*)(hb + (size_t)N * C);
    float* ad = as + N;
    int* row_start     = (int*)(ad + N);
    uint32* packed     = (uint32*)(row_start + (N + 2));
    uint32* csr        = packed + total;
    uint32* Wf         = csr + total;
    int* bucket_cnt    = (int*)(Wf + 8192);
    int* bucket_off    = bucket_cnt + NB;
    int* bucket_cursor = bucket_off + (NB + 1);

    cvtw_kernel<<<32, 256, 0, stream>>>(W, Wf, bucket_cnt, NB);
    gemm_hist_kernel<<<(N + 63) / 64, 256, 0, stream>>>(
        x, Wf, a_src, a_dst, hb, as, ad, N, dst, bucket_cnt, E, total, NB);
    scan_off_kernel<<<1, 256, 0, stream>>>(bucket_cnt, bucket_off, bucket_cursor,
                                           row_start, NB, N, total);
    bin_kernel<<<(total + BIN_CHUNK - 1) / BIN_CHUNK, 1024, 0, stream>>>(
        src, dst, bucket_cursor, packed, E, total, NB);
    build_kernel<<<NB, 1024, 0, stream>>>(packed, bucket_off, as, ad, row_start, csr, N);
    gather_kernel<<<(N + 3) / 4, 256, 0, stream>>>(csr, row_start, hb, bias, out, N);
}